// Round 11
// baseline (431.733 us; speedup 1.0000x reference)
//
#include <hip/hip_runtime.h>
#include <math.h>

// Quantum conv layer: 4-qubit circuit per 2x2 patch of [64,128,128,1] images.
//
// Math: out_q(patch) = T01^T * C_q * T23, where
//   f_i  = (1, cos(theta_i), sin(theta_i))       (per-pixel, double-angle form)
//   T01  = f_TL (x) f_TR,  T23 = f_BL (x) f_BR   (9-vecs)
//   C_q  = 9x9 real tensor from the 8 circuit weights (patch-independent).
//
// SINGLE fused kernel. HISTORY (measured on MI355X):
//  - r2 fused (libm sincos, px staging): 184 VGPR, occ 10.8%, 102 us.
//  - r5 split + __launch_bounds__(256,4): 64 VGPR forced -> 1.3 GB scratch
//    spill, 420 us. Tripwire: FETCH ballooning = spill.
//  - r7 split + __sincosf: main 41.9 us, 184 VGPR (allocator bloat is from
//    the MAIN loop, not setup), VALUBusy 26.5%, FETCH/WRITE ideal.
//  - r8 C via s_load instead of LDS: neutral (~40 us) -> NOT LDS-issue-bound.
//  - Cross-round: each kernel node costs ~25 us of graph overhead
//    (r2: dur-kernel=25.4 with 1 node; r5/r7/r8: 48-55 with 2 nodes).
//    => fuse back to ONE node; amortize per-block C-build over 1024 patches.

#define HO 127
#define WO 127
#define HH 128
#define WW 128

__global__ __launch_bounds__(256)
__attribute__((amdgpu_waves_per_eu(4)))   // cap VGPR ~128 -> 4 blocks/CU
void qconv_fused(const float* __restrict__ images,
                 const float* __restrict__ weights,
                 float* __restrict__ out)
{
    __shared__ float Ur[16][16], Ui[16][16];  // U[s][t]: circuit on basis |t>
    __shared__ float Amat[4][16][16];         // A_q = Re(U^H Z_q U)
    __shared__ float C[4][9][12];             // rows padded to 12 -> b128 reads

    const int tid = threadIdx.x;

    // ---- phase 1 (lanes 0-15): simulate the 16 basis columns of U ----
    // Register state confined to 16 lanes; r7 proved this is not the VGPR
    // driver. Other waves wait ~2400 cyc once per block; hidden by the other
    // resident blocks' compute.
    if (tid < 16) {
        float sr[16], si[16];
        #pragma unroll
        for (int s = 0; s < 16; ++s) { sr[s] = 0.f; si[s] = 0.f; }
        sr[tid] = 1.f;
        for (int l = 0; l < 2; ++l) {
            for (int q = 0; q < 4; ++q) {           // RX(w[l][q]), qubit0 = MSB
                float w = weights[l*4 + q];
                float ch, sh;
                __sincosf(0.5f*w, &sh, &ch);
                const int bit = 1 << (3 - q);
                for (int s0 = 0; s0 < 16; ++s0) {
                    if (s0 & bit) continue;
                    const int s1 = s0 | bit;
                    float a0r = sr[s0], a0i = si[s0];
                    float a1r = sr[s1], a1i = si[s1];
                    sr[s0] = fmaf(ch, a0r,  sh*a1i);   // c*a0 - i*s*a1
                    si[s0] = fmaf(ch, a0i, -sh*a1r);
                    sr[s1] = fmaf(ch, a1r,  sh*a0i);   // -i*s*a0 + c*a1
                    si[s1] = fmaf(ch, a1i, -sh*a0r);
                }
            }
            for (int q = 0; q < 4; ++q) {           // CNOT ring q -> (q+1)%4
                const int bc = 1 << (3 - q), bt = 1 << (3 - ((q+1)&3));
                for (int s0 = 0; s0 < 16; ++s0) {
                    if ((s0 & bc) && !(s0 & bt)) {
                        const int s1 = s0 | bt;
                        float tr = sr[s0], ti = si[s0];
                        sr[s0] = sr[s1]; si[s0] = si[s1];
                        sr[s1] = tr;     si[s1] = ti;
                    }
                }
            }
        }
        #pragma unroll
        for (int s = 0; s < 16; ++s) { Ur[s][tid] = sr[s]; Ui[s][tid] = si[s]; }
    }
    __syncthreads();

    // ---- phase 2: A_q[t][t'] = sum_s sign_q(s) * Re(conj(U[s,t]) U[s,t']) ----
    for (int e = tid; e < 1024; e += 256) {
        int q = e >> 8, t = (e >> 4) & 15, tp = e & 15;
        float acc = 0.f;
        #pragma unroll
        for (int s = 0; s < 16; ++s) {
            float d = Ur[s][t]*Ur[s][tp] + Ui[s][t]*Ui[s][tp];
            acc += ((s >> (3 - q)) & 1) ? -d : d;
        }
        Amat[q][t][tp] = acc;
    }
    __syncthreads();

    // ---- phase 3: coefficient tensor. k in {0,1,2}^4: the (t,t') double sum
    // collapses to t' = t ^ mask(k_i==2), weight (1/16)*prod_{k_i==1}(1-2t_i)
    for (int e = tid; e < 324; e += 256) {     // grid-stride: 324 > 256
        int q = e / 81, kk = e % 81;
        int k0 = kk/27, k1 = (kk/9)%3, k2 = (kk/3)%3, k3 = kk%3;
        int mask = 0, sb = 0;
        if (k0 == 2) mask |= 8; else if (k0 == 1) sb |= 8;
        if (k1 == 2) mask |= 4; else if (k1 == 1) sb |= 4;
        if (k2 == 2) mask |= 2; else if (k2 == 1) sb |= 2;
        if (k3 == 2) mask |= 1; else if (k3 == 1) sb |= 1;
        float acc = 0.f;
        #pragma unroll
        for (int t = 0; t < 16; ++t) {
            float a = Amat[q][t][t ^ mask];
            acc += (__popc(t & sb) & 1) ? -a : a;
        }
        C[q][k0*3 + k1][k2*3 + k3] = acc * 0.0625f;
    }
    __syncthreads();

    // ---- patch evaluation: 2 y-iters x (2 vertical patches / thread) ----
    // Direct pixel loads (4 MB image set is L2/L3-resident; no staging
    // barrier), __sincosf hw trig (theta in [0,pi); err ~1e-6 vs 2e-3 margin).
    const int tx  = tid & 15, ty = tid >> 4;
    const int x0  = blockIdx.x * 16;
    const int b   = blockIdx.z;
    const float* img = images + (size_t)b * (HH*WW);
    const int c   = x0 + tx;
    const int gx0 = min(c,     WW - 1);
    const int gx1 = min(c + 1, WW - 1);

    #pragma unroll 1
    for (int yi = 0; yi < 2; ++yi) {
        const int rA = blockIdx.y*64 + yi*32 + 2*ty;   // patch A row; B = rA+1
        const int r0 = min(rA,     HH - 1);
        const int r1 = min(rA + 1, HH - 1);
        const int r2 = min(rA + 2, HH - 1);

        float a00 = img[r0*WW + gx0], a01 = img[r0*WW + gx1];
        float a10 = img[r1*WW + gx0], a11 = img[r1*WW + gx1];
        float a20 = img[r2*WW + gx0], a21 = img[r2*WW + gx1];

        float2 p0L, p0R, p1L, p1R, p2L, p2R;
        __sincosf(a00, &p0L.y, &p0L.x);  __sincosf(a01, &p0R.y, &p0R.x);
        __sincosf(a10, &p1L.y, &p1L.x);  __sincosf(a11, &p1R.y, &p1R.x);
        __sincosf(a20, &p2L.y, &p2L.x);  __sincosf(a21, &p2R.y, &p2R.x);

        float T0[9], T1[9], T2[9];
        T0[0]=1.f;   T0[1]=p0R.x;       T0[2]=p0R.y;
        T0[3]=p0L.x; T0[4]=p0L.x*p0R.x; T0[5]=p0L.x*p0R.y;
        T0[6]=p0L.y; T0[7]=p0L.y*p0R.x; T0[8]=p0L.y*p0R.y;
        T1[0]=1.f;   T1[1]=p1R.x;       T1[2]=p1R.y;
        T1[3]=p1L.x; T1[4]=p1L.x*p1R.x; T1[5]=p1L.x*p1R.y;
        T1[6]=p1L.y; T1[7]=p1L.y*p1R.x; T1[8]=p1L.y*p1R.y;
        T2[0]=1.f;   T2[1]=p2R.x;       T2[2]=p2R.y;
        T2[3]=p2L.x; T2[4]=p2L.x*p2R.x; T2[5]=p2L.x*p2R.y;
        T2[6]=p2L.y; T2[7]=p2L.y*p2R.x; T2[8]=p2L.y*p2R.y;

        float oA[4], oB[4];
        #pragma unroll
        for (int q = 0; q < 4; ++q) {
            float accA = 0.f, accB = 0.f;
            #pragma unroll
            for (int i = 0; i < 9; ++i) {
                const float* row = &C[q][i][0];
                float4 ra = *reinterpret_cast<const float4*>(row);  // broadcast
                float4 rb = *reinterpret_cast<const float4*>(row + 4);
                float  r8 = row[8];
                float dA = ra.x, dB = ra.x;             // T[0] == 1
                dA = fmaf(ra.y, T1[1], dA);  dB = fmaf(ra.y, T2[1], dB);
                dA = fmaf(ra.z, T1[2], dA);  dB = fmaf(ra.z, T2[2], dB);
                dA = fmaf(ra.w, T1[3], dA);  dB = fmaf(ra.w, T2[3], dB);
                dA = fmaf(rb.x, T1[4], dA);  dB = fmaf(rb.x, T2[4], dB);
                dA = fmaf(rb.y, T1[5], dA);  dB = fmaf(rb.y, T2[5], dB);
                dA = fmaf(rb.z, T1[6], dA);  dB = fmaf(rb.z, T2[6], dB);
                dA = fmaf(rb.w, T1[7], dA);  dB = fmaf(rb.w, T2[7], dB);
                dA = fmaf(r8,   T1[8], dA);  dB = fmaf(r8,   T2[8], dB);
                accA = fmaf(T0[i], dA, accA);
                accB = fmaf(T1[i], dB, accB);
            }
            oA[q] = accA; oB[q] = accB;
        }

        if (c < WO) {
            if (rA < HO)
                *reinterpret_cast<float4*>(out + ((size_t)((size_t)b*HO + rA)*WO + c)*4) =
                    make_float4(oA[0], oA[1], oA[2], oA[3]);
            if (rA + 1 < HO)
                *reinterpret_cast<float4*>(out + ((size_t)((size_t)b*HO + rA+1)*WO + c)*4) =
                    make_float4(oB[0], oB[1], oB[2], oB[3]);
        }
    }
}

extern "C" void kernel_launch(void* const* d_in, const int* in_sizes, int n_in,
                              void* d_out, int out_size, void* d_ws, size_t ws_size,
                              hipStream_t stream) {
    const float* images  = (const float*)d_in[0];   // [64,128,128,1]
    const float* weights = (const float*)d_in[1];   // [2,4]
    float* outp = (float*)d_out;                    // [64,127,127,4]

    // ONE kernel node: each node costs ~25 us of graph overhead (measured
    // r2 vs r5/r7/r8), so the split-setup design wastes more than the
    // per-block redundant C-build (~2-3 us total, hidden by co-resident
    // blocks).
    dim3 grid(8, 2, 64);   // 16 cols x 64 rows per block (x2 y-iters), 1024 blocks
    qconv_fused<<<grid, dim3(256,1,1), 0, stream>>>(images, weights, outp);
}

// Round 13
// 93.731 us; speedup vs baseline: 4.6061x; 4.6061x over previous
//
#include <hip/hip_runtime.h>
#include <math.h>

// Quantum conv layer: 4-qubit circuit per 2x2 patch of [64,128,128,1] images.
//
// Math: out_q(patch) = T01^T * C_q * T23, where
//   f_i  = (1, cos(theta_i), sin(theta_i))       (per-pixel, double-angle form)
//   T01  = f_TL (x) f_TR,  T23 = f_BL (x) f_BR   (9-vecs)
//   C_q  = 9x9 real tensor from the 8 circuit weights (patch-independent).
//
// SINGLE fused kernel, NO occupancy attributes. HISTORY (measured, MI355X):
//  - r2 fused (libm sincos, px staging): 184 VGPR, occ 10.8%, 102 us.
//  - r5 split + __launch_bounds__(256,4): compiler -> 64 VGPR -> 1.3 GB
//    scratch spill, 420 us, VALUBusy 2%.
//  - r7 split + __sincosf, plain bounds: 184 VGPR, NO spill, main 41.9 us,
//    VALUBusy 26.5%, FETCH/WRITE ideal (5.7/17.1 MB).
//  - r8 C via s_load: neutral -> not LDS-issue-bound.
//  - r11 fused + amdgpu_waves_per_eu(4): SAME 64-VGPR spill signature as r5
//    (FETCH 654 MB, 385 us, occ 44% yet 10x slower). BOTH occupancy hints
//    bind VGPR=64 on gfx950; the unrolled body needs ~100+. Occupancy was
//    never the scarce resource — not-spilling is. NEVER re-add them.
//  - Overhead model: dur_us ~= harness fill (~45 us) + ~25 us/kernel-node
//    + kernel time. => ONE node, unconstrained allocator.

#define HO 127
#define WO 127
#define HH 128
#define WW 128

__global__ __launch_bounds__(256)
void qconv_fused(const float* __restrict__ images,
                 const float* __restrict__ weights,
                 float* __restrict__ out)
{
    __shared__ float Ur[16][16], Ui[16][16];  // U[s][t]: circuit on basis |t>
    __shared__ float Amat[4][16][16];         // A_q = Re(U^H Z_q U)
    __shared__ float C[4][9][12];             // rows padded to 12 -> b128 reads

    const int tid = threadIdx.x;

    // ---- phase 1 (lanes 0-15): simulate the 16 basis columns of U ----
    if (tid < 16) {
        float sr[16], si[16];
        #pragma unroll
        for (int s = 0; s < 16; ++s) { sr[s] = 0.f; si[s] = 0.f; }
        sr[tid] = 1.f;
        for (int l = 0; l < 2; ++l) {
            for (int q = 0; q < 4; ++q) {           // RX(w[l][q]), qubit0 = MSB
                float w = weights[l*4 + q];
                float ch, sh;
                __sincosf(0.5f*w, &sh, &ch);
                const int bit = 1 << (3 - q);
                for (int s0 = 0; s0 < 16; ++s0) {
                    if (s0 & bit) continue;
                    const int s1 = s0 | bit;
                    float a0r = sr[s0], a0i = si[s0];
                    float a1r = sr[s1], a1i = si[s1];
                    sr[s0] = fmaf(ch, a0r,  sh*a1i);   // c*a0 - i*s*a1
                    si[s0] = fmaf(ch, a0i, -sh*a1r);
                    sr[s1] = fmaf(ch, a1r,  sh*a0i);   // -i*s*a0 + c*a1
                    si[s1] = fmaf(ch, a1i, -sh*a0r);
                }
            }
            for (int q = 0; q < 4; ++q) {           // CNOT ring q -> (q+1)%4
                const int bc = 1 << (3 - q), bt = 1 << (3 - ((q+1)&3));
                for (int s0 = 0; s0 < 16; ++s0) {
                    if ((s0 & bc) && !(s0 & bt)) {
                        const int s1 = s0 | bt;
                        float tr = sr[s0], ti = si[s0];
                        sr[s0] = sr[s1]; si[s0] = si[s1];
                        sr[s1] = tr;     si[s1] = ti;
                    }
                }
            }
        }
        #pragma unroll
        for (int s = 0; s < 16; ++s) { Ur[s][tid] = sr[s]; Ui[s][tid] = si[s]; }
    }
    __syncthreads();

    // ---- phase 2: A_q[t][t'] = sum_s sign_q(s) * Re(conj(U[s,t]) U[s,t']) ----
    for (int e = tid; e < 1024; e += 256) {
        int q = e >> 8, t = (e >> 4) & 15, tp = e & 15;
        float acc = 0.f;
        #pragma unroll
        for (int s = 0; s < 16; ++s) {
            float d = Ur[s][t]*Ur[s][tp] + Ui[s][t]*Ui[s][tp];
            acc += ((s >> (3 - q)) & 1) ? -d : d;
        }
        Amat[q][t][tp] = acc;
    }
    __syncthreads();

    // ---- phase 3: coefficient tensor. k in {0,1,2}^4: the (t,t') double sum
    // collapses to t' = t ^ mask(k_i==2), weight (1/16)*prod_{k_i==1}(1-2t_i)
    for (int e = tid; e < 324; e += 256) {     // grid-stride: 324 > 256
        int q = e / 81, kk = e % 81;
        int k0 = kk/27, k1 = (kk/9)%3, k2 = (kk/3)%3, k3 = kk%3;
        int mask = 0, sb = 0;
        if (k0 == 2) mask |= 8; else if (k0 == 1) sb |= 8;
        if (k1 == 2) mask |= 4; else if (k1 == 1) sb |= 4;
        if (k2 == 2) mask |= 2; else if (k2 == 1) sb |= 2;
        if (k3 == 2) mask |= 1; else if (k3 == 1) sb |= 1;
        float acc = 0.f;
        #pragma unroll
        for (int t = 0; t < 16; ++t) {
            float a = Amat[q][t][t ^ mask];
            acc += (__popc(t & sb) & 1) ? -a : a;
        }
        C[q][k0*3 + k1][k2*3 + k3] = acc * 0.0625f;
    }
    __syncthreads();

    // ---- patch evaluation: 2 y-iters x (2 vertical patches / thread) ----
    // Direct pixel loads (4 MB image set is L2/L3-resident; no staging
    // barrier), __sincosf hw trig (theta in [0,pi); err ~1e-6 vs 2e-3 margin).
    const int tx  = tid & 15, ty = tid >> 4;
    const int x0  = blockIdx.x * 16;
    const int b   = blockIdx.z;
    const float* img = images + (size_t)b * (HH*WW);
    const int c   = x0 + tx;
    const int gx0 = min(c,     WW - 1);
    const int gx1 = min(c + 1, WW - 1);

    #pragma unroll 1
    for (int yi = 0; yi < 2; ++yi) {
        const int rA = blockIdx.y*64 + yi*32 + 2*ty;   // patch A row; B = rA+1
        const int r0 = min(rA,     HH - 1);
        const int r1 = min(rA + 1, HH - 1);
        const int r2 = min(rA + 2, HH - 1);

        float a00 = img[r0*WW + gx0], a01 = img[r0*WW + gx1];
        float a10 = img[r1*WW + gx0], a11 = img[r1*WW + gx1];
        float a20 = img[r2*WW + gx0], a21 = img[r2*WW + gx1];

        float2 p0L, p0R, p1L, p1R, p2L, p2R;
        __sincosf(a00, &p0L.y, &p0L.x);  __sincosf(a01, &p0R.y, &p0R.x);
        __sincosf(a10, &p1L.y, &p1L.x);  __sincosf(a11, &p1R.y, &p1R.x);
        __sincosf(a20, &p2L.y, &p2L.x);  __sincosf(a21, &p2R.y, &p2R.x);

        float T0[9], T1[9], T2[9];
        T0[0]=1.f;   T0[1]=p0R.x;       T0[2]=p0R.y;
        T0[3]=p0L.x; T0[4]=p0L.x*p0R.x; T0[5]=p0L.x*p0R.y;
        T0[6]=p0L.y; T0[7]=p0L.y*p0R.x; T0[8]=p0L.y*p0R.y;
        T1[0]=1.f;   T1[1]=p1R.x;       T1[2]=p1R.y;
        T1[3]=p1L.x; T1[4]=p1L.x*p1R.x; T1[5]=p1L.x*p1R.y;
        T1[6]=p1L.y; T1[7]=p1L.y*p1R.x; T1[8]=p1L.y*p1R.y;
        T2[0]=1.f;   T2[1]=p2R.x;       T2[2]=p2R.y;
        T2[3]=p2L.x; T2[4]=p2L.x*p2R.x; T2[5]=p2L.x*p2R.y;
        T2[6]=p2L.y; T2[7]=p2L.y*p2R.x; T2[8]=p2L.y*p2R.y;

        float oA[4], oB[4];
        #pragma unroll
        for (int q = 0; q < 4; ++q) {
            float accA = 0.f, accB = 0.f;
            #pragma unroll
            for (int i = 0; i < 9; ++i) {
                const float* row = &C[q][i][0];
                float4 ra = *reinterpret_cast<const float4*>(row);  // broadcast
                float4 rb = *reinterpret_cast<const float4*>(row + 4);
                float  r8 = row[8];
                float dA = ra.x, dB = ra.x;             // T[0] == 1
                dA = fmaf(ra.y, T1[1], dA);  dB = fmaf(ra.y, T2[1], dB);
                dA = fmaf(ra.z, T1[2], dA);  dB = fmaf(ra.z, T2[2], dB);
                dA = fmaf(ra.w, T1[3], dA);  dB = fmaf(ra.w, T2[3], dB);
                dA = fmaf(rb.x, T1[4], dA);  dB = fmaf(rb.x, T2[4], dB);
                dA = fmaf(rb.y, T1[5], dA);  dB = fmaf(rb.y, T2[5], dB);
                dA = fmaf(rb.z, T1[6], dA);  dB = fmaf(rb.z, T2[6], dB);
                dA = fmaf(rb.w, T1[7], dA);  dB = fmaf(rb.w, T2[7], dB);
                dA = fmaf(r8,   T1[8], dA);  dB = fmaf(r8,   T2[8], dB);
                accA = fmaf(T0[i], dA, accA);
                accB = fmaf(T1[i], dB, accB);
            }
            oA[q] = accA; oB[q] = accB;
        }

        if (c < WO) {
            if (rA < HO)
                *reinterpret_cast<float4*>(out + ((size_t)((size_t)b*HO + rA)*WO + c)*4) =
                    make_float4(oA[0], oA[1], oA[2], oA[3]);
            if (rA + 1 < HO)
                *reinterpret_cast<float4*>(out + ((size_t)((size_t)b*HO + rA+1)*WO + c)*4) =
                    make_float4(oB[0], oB[1], oB[2], oB[3]);
        }
    }
}

extern "C" void kernel_launch(void* const* d_in, const int* in_sizes, int n_in,
                              void* d_out, int out_size, void* d_ws, size_t ws_size,
                              hipStream_t stream) {
    const float* images  = (const float*)d_in[0];   // [64,128,128,1]
    const float* weights = (const float*)d_in[1];   // [2,4]
    float* outp = (float*)d_out;                    // [64,127,127,4]

    // ONE kernel node (each node ~25 us of graph overhead, measured r2 vs
    // r5/r7/r8). Per-block redundant C-build is ~2-3 us total, hidden by
    // co-resident blocks.
    dim3 grid(8, 2, 64);   // 16 cols x 64 rows per block (x2 y-iters), 1024 blocks
    qconv_fused<<<grid, dim3(256,1,1), 0, stream>>>(images, weights, outp);
}

// Round 14
// 85.920 us; speedup vs baseline: 5.0248x; 1.0909x over previous
//
#include <hip/hip_runtime.h>
#include <math.h>

// Quantum conv layer: 4-qubit circuit per 2x2 patch of [64,128,128,1] images.
//
// Math: out_q(patch) = T01^T * C_q * T23, where
//   f_i  = (1, cos(theta_i), sin(theta_i))       (per-pixel, double-angle form)
//   T01  = f_TL (x) f_TR,  T23 = f_BL (x) f_BR   (9-vecs)
//   C_q  = 9x9 real tensor from the 8 circuit weights (patch-independent).
//
// SINGLE fused kernel, NO occupancy attributes. HISTORY (measured, MI355X):
//  - r5/r11: BOTH occupancy hints (__launch_bounds__(256,4) AND
//    amdgpu_waves_per_eu(4)) bind VGPR=64 on gfx950 -> ~1 GB scratch spill,
//    385-420 us, VALUBusy 2-3%. NEVER re-add them. Spill tripwire: FETCH >> 20 MB.
//  - r7 split two-node: main 41.9 us (184 VGPR, px staged in LDS), total 95.4.
//  - r13 fused one-node, direct pixel loads, 1024 blocks: kernel 61.5,
//    dur 93.7. Gap vs r7 main: (a) setup paid 2x/CU (2 block-rounds),
//    (b) direct loads: 12 sincosf + 12 scattered global loads/thread vs
//    staged ~2.3 (VALU packed 11.1 -> 14.1 us + unhidden load latency).
//  - THIS round: 512 blocks (= exactly 2/CU -> setup paid once, concurrent)
//    + restore px LDS staging (overlapped with wave-0 circuit simulation).

#define HO 127
#define WO 127
#define HH 128
#define WW 128

__global__ __launch_bounds__(256)
void qconv_fused(const float* __restrict__ images,
                 const float* __restrict__ weights,
                 float* __restrict__ out)
{
    __shared__ float  Ur[16][16], Ui[16][16]; // U[s][t]: circuit on basis |t>
    __shared__ float  Amat[4][16][16];        // A_q = Re(U^H Z_q U)
    __shared__ float  C[4][9][12];            // rows padded to 12 -> b128 reads
    __shared__ float2 px[129][17];            // (cos,sin) per pixel, 16x128 tile+halo

    const int tid = threadIdx.x;
    const int x0  = blockIdx.x * 16;
    const int b   = blockIdx.z;
    const float* img = images + (size_t)b * (HH*WW);

    // ---- phase 1 (lanes 0-15): simulate the 16 basis columns of U ----
    // ---- concurrently (tid 16-255): stage pixel sincos into LDS      ----
    if (tid < 16) {
        float sr[16], si[16];
        #pragma unroll
        for (int s = 0; s < 16; ++s) { sr[s] = 0.f; si[s] = 0.f; }
        sr[tid] = 1.f;
        for (int l = 0; l < 2; ++l) {
            for (int q = 0; q < 4; ++q) {           // RX(w[l][q]), qubit0 = MSB
                float w = weights[l*4 + q];
                float ch, sh;
                __sincosf(0.5f*w, &sh, &ch);
                const int bit = 1 << (3 - q);
                for (int s0 = 0; s0 < 16; ++s0) {
                    if (s0 & bit) continue;
                    const int s1 = s0 | bit;
                    float a0r = sr[s0], a0i = si[s0];
                    float a1r = sr[s1], a1i = si[s1];
                    sr[s0] = fmaf(ch, a0r,  sh*a1i);   // c*a0 - i*s*a1
                    si[s0] = fmaf(ch, a0i, -sh*a1r);
                    sr[s1] = fmaf(ch, a1r,  sh*a0i);   // -i*s*a0 + c*a1
                    si[s1] = fmaf(ch, a1i, -sh*a0r);
                }
            }
            for (int q = 0; q < 4; ++q) {           // CNOT ring q -> (q+1)%4
                const int bc = 1 << (3 - q), bt = 1 << (3 - ((q+1)&3));
                for (int s0 = 0; s0 < 16; ++s0) {
                    if ((s0 & bc) && !(s0 & bt)) {
                        const int s1 = s0 | bt;
                        float tr = sr[s0], ti = si[s0];
                        sr[s0] = sr[s1]; si[s0] = si[s1];
                        sr[s1] = tr;     si[s1] = ti;
                    }
                }
            }
        }
        #pragma unroll
        for (int s = 0; s < 16; ++s) { Ur[s][tid] = sr[s]; Ui[s][tid] = si[s]; }
    } else {
        for (int idx = tid - 16; idx < 129*17; idx += 240) {
            int py = idx / 17, pc = idx - py*17;
            int gy = min(py, HH - 1);
            int gx = min(x0 + pc, WW - 1);
            float th = img[gy*WW + gx];
            float sn, cs;
            __sincosf(th, &sn, &cs);
            px[py][pc] = make_float2(cs, sn);
        }
    }
    __syncthreads();

    // ---- phase 2: A_q[t][t'] = sum_s sign_q(s) * Re(conj(U[s,t]) U[s,t']) ----
    for (int e = tid; e < 1024; e += 256) {
        int q = e >> 8, t = (e >> 4) & 15, tp = e & 15;
        float acc = 0.f;
        #pragma unroll
        for (int s = 0; s < 16; ++s) {
            float d = Ur[s][t]*Ur[s][tp] + Ui[s][t]*Ui[s][tp];
            acc += ((s >> (3 - q)) & 1) ? -d : d;
        }
        Amat[q][t][tp] = acc;
    }
    __syncthreads();

    // ---- phase 3: coefficient tensor. k in {0,1,2}^4: the (t,t') double sum
    // collapses to t' = t ^ mask(k_i==2), weight (1/16)*prod_{k_i==1}(1-2t_i)
    for (int e = tid; e < 324; e += 256) {     // grid-stride: 324 > 256
        int q = e / 81, kk = e % 81;
        int k0 = kk/27, k1 = (kk/9)%3, k2 = (kk/3)%3, k3 = kk%3;
        int mask = 0, sb = 0;
        if (k0 == 2) mask |= 8; else if (k0 == 1) sb |= 8;
        if (k1 == 2) mask |= 4; else if (k1 == 1) sb |= 4;
        if (k2 == 2) mask |= 2; else if (k2 == 1) sb |= 2;
        if (k3 == 2) mask |= 1; else if (k3 == 1) sb |= 1;
        float acc = 0.f;
        #pragma unroll
        for (int t = 0; t < 16; ++t) {
            float a = Amat[q][t][t ^ mask];
            acc += (__popc(t & sb) & 1) ? -a : a;
        }
        C[q][k0*3 + k1][k2*3 + k3] = acc * 0.0625f;
    }
    __syncthreads();

    // ---- patch evaluation: 4 y-iters x (2 vertical patches / thread) ----
    const int tx = tid & 15, ty = tid >> 4;
    const int c  = x0 + tx;

    #pragma unroll 1
    for (int yi = 0; yi < 4; ++yi) {
        const int rA = yi*32 + 2*ty;           // patch A row; B = rA+1 (max 126)

        float2 p0L = px[rA  ][tx], p0R = px[rA  ][tx+1];
        float2 p1L = px[rA+1][tx], p1R = px[rA+1][tx+1];
        float2 p2L = px[rA+2][tx], p2R = px[rA+2][tx+1];

        float T0[9], T1[9], T2[9];
        T0[0]=1.f;   T0[1]=p0R.x;       T0[2]=p0R.y;
        T0[3]=p0L.x; T0[4]=p0L.x*p0R.x; T0[5]=p0L.x*p0R.y;
        T0[6]=p0L.y; T0[7]=p0L.y*p0R.x; T0[8]=p0L.y*p0R.y;
        T1[0]=1.f;   T1[1]=p1R.x;       T1[2]=p1R.y;
        T1[3]=p1L.x; T1[4]=p1L.x*p1R.x; T1[5]=p1L.x*p1R.y;
        T1[6]=p1L.y; T1[7]=p1L.y*p1R.x; T1[8]=p1L.y*p1R.y;
        T2[0]=1.f;   T2[1]=p2R.x;       T2[2]=p2R.y;
        T2[3]=p2L.x; T2[4]=p2L.x*p2R.x; T2[5]=p2L.x*p2R.y;
        T2[6]=p2L.y; T2[7]=p2L.y*p2R.x; T2[8]=p2L.y*p2R.y;

        float oA[4], oB[4];
        #pragma unroll
        for (int q = 0; q < 4; ++q) {
            float accA = 0.f, accB = 0.f;
            #pragma unroll
            for (int i = 0; i < 9; ++i) {
                const float* row = &C[q][i][0];
                float4 ra = *reinterpret_cast<const float4*>(row);  // broadcast
                float4 rb = *reinterpret_cast<const float4*>(row + 4);
                float  r8 = row[8];
                float dA = ra.x, dB = ra.x;             // T[0] == 1
                dA = fmaf(ra.y, T1[1], dA);  dB = fmaf(ra.y, T2[1], dB);
                dA = fmaf(ra.z, T1[2], dA);  dB = fmaf(ra.z, T2[2], dB);
                dA = fmaf(ra.w, T1[3], dA);  dB = fmaf(ra.w, T2[3], dB);
                dA = fmaf(rb.x, T1[4], dA);  dB = fmaf(rb.x, T2[4], dB);
                dA = fmaf(rb.y, T1[5], dA);  dB = fmaf(rb.y, T2[5], dB);
                dA = fmaf(rb.z, T1[6], dA);  dB = fmaf(rb.z, T2[6], dB);
                dA = fmaf(rb.w, T1[7], dA);  dB = fmaf(rb.w, T2[7], dB);
                dA = fmaf(r8,   T1[8], dA);  dB = fmaf(r8,   T2[8], dB);
                accA = fmaf(T0[i], dA, accA);
                accB = fmaf(T1[i], dB, accB);
            }
            oA[q] = accA; oB[q] = accB;
        }

        if (c < WO) {
            // rA <= 126 < HO always; guard only row rA+1
            *reinterpret_cast<float4*>(out + ((size_t)((size_t)b*HO + rA)*WO + c)*4) =
                make_float4(oA[0], oA[1], oA[2], oA[3]);
            if (rA + 1 < HO)
                *reinterpret_cast<float4*>(out + ((size_t)((size_t)b*HO + rA+1)*WO + c)*4) =
                    make_float4(oB[0], oB[1], oB[2], oB[3]);
        }
    }
}

extern "C" void kernel_launch(void* const* d_in, const int* in_sizes, int n_in,
                              void* d_out, int out_size, void* d_ws, size_t ws_size,
                              hipStream_t stream) {
    const float* images  = (const float*)d_in[0];   // [64,128,128,1]
    const float* weights = (const float*)d_in[1];   // [2,4]
    float* outp = (float*)d_out;                    // [64,127,127,4]

    // 512 blocks = exactly 2 per CU (188 VGPR -> 2 co-resident): every CU
    // pays the per-block C-build ONCE, both resident blocks' setups overlap.
    dim3 grid(8, 1, 64);   // 16 cols x 127 patch-rows per block (4 y-iters)
    qconv_fused<<<grid, dim3(256,1,1), 0, stream>>>(images, weights, outp);
}

// Round 15
// 67.683 us; speedup vs baseline: 6.3788x; 1.2695x over previous
//
#include <hip/hip_runtime.h>
#include <math.h>

// Quantum conv layer: 4-qubit circuit per 2x2 patch of [64,128,128,1] images.
//
// Math: out_q(patch) = T01^T * C_q * T23, f_i = (1, cos th_i, sin th_i),
// C_q from the 8 circuit weights. SPARSITY (derived via Pauli conjugation,
// verified at zero weights for all q): C_q has only 12 structural nonzeros:
//   C0: (4,1),(4,7)  C1: (3,4),(5,4)
//   C2: (1,1),(1,7),(7,1),(7,7)  C3: (3,3),(3,5),(5,3),(5,5)
// (i=k0*3+k1, j=k2*3+k3, k: 0=I,1=Z(cos),2=X(sin); qubit0=MSB).
// Values still come from the generic (measured-correct) phase 1-3 build;
// only the POSITIONS are exploited. Wrong positions => loud absmax fail.
//
// HISTORY (measured, MI355X):
//  - r5/r11: occupancy hints (__launch_bounds__(256,4) / amdgpu_waves_per_eu)
//    bind VGPR=64 -> ~1 GB scratch spill, 385-420 us. NEVER re-add.
//    Spill tripwire: FETCH >> 20 MB.
//  - r13 fused 1024 blocks, direct loads: kernel 61.5, dur 93.7.
//  - r14 fused 512 blocks + px staging: kernel ~40, dur 85.9. Top-5 = harness
//    256 MB d_ws poison fills (~42 us, inside timed window) -> dur floor ~46.
//    Kernel cost: LDS C-row issue (~432 ds_read/thread) + stalls, NOT FMA.
//  - THIS round: sparse 12-coeff main loop (45 VALU + 6 ds_read per pair/yi
//    vs ~750 + 27) -> kernel should drop to setup+staging floor.

#define HO 127
#define WO 127
#define HH 128
#define WW 128

__global__ __launch_bounds__(256)
void qconv_fused(const float* __restrict__ images,
                 const float* __restrict__ weights,
                 float* __restrict__ out)
{
    __shared__ float  Ur[16][16], Ui[16][16]; // U[s][t]: circuit on basis |t>
    __shared__ float  Amat[4][16][16];        // A_q = Re(U^H Z_q U)
    __shared__ float  C[4][9][12];            // coefficient tensor (padded)
    __shared__ float2 px[129][17];            // (cos,sin) per pixel, tile+halo

    const int tid = threadIdx.x;
    const int x0  = blockIdx.x * 16;
    const int b   = blockIdx.z;
    const float* img = images + (size_t)b * (HH*WW);

    // ---- phase 1 (lanes 0-15): simulate the 16 basis columns of U ----
    // ---- concurrently (tid 16-255): stage pixel sincos into LDS      ----
    if (tid < 16) {
        float sr[16], si[16];
        #pragma unroll
        for (int s = 0; s < 16; ++s) { sr[s] = 0.f; si[s] = 0.f; }
        sr[tid] = 1.f;
        for (int l = 0; l < 2; ++l) {
            for (int q = 0; q < 4; ++q) {           // RX(w[l][q]), qubit0 = MSB
                float w = weights[l*4 + q];
                float ch, sh;
                __sincosf(0.5f*w, &sh, &ch);
                const int bit = 1 << (3 - q);
                for (int s0 = 0; s0 < 16; ++s0) {
                    if (s0 & bit) continue;
                    const int s1 = s0 | bit;
                    float a0r = sr[s0], a0i = si[s0];
                    float a1r = sr[s1], a1i = si[s1];
                    sr[s0] = fmaf(ch, a0r,  sh*a1i);   // c*a0 - i*s*a1
                    si[s0] = fmaf(ch, a0i, -sh*a1r);
                    sr[s1] = fmaf(ch, a1r,  sh*a0i);   // -i*s*a0 + c*a1
                    si[s1] = fmaf(ch, a1i, -sh*a0r);
                }
            }
            for (int q = 0; q < 4; ++q) {           // CNOT ring q -> (q+1)%4
                const int bc = 1 << (3 - q), bt = 1 << (3 - ((q+1)&3));
                for (int s0 = 0; s0 < 16; ++s0) {
                    if ((s0 & bc) && !(s0 & bt)) {
                        const int s1 = s0 | bt;
                        float tr = sr[s0], ti = si[s0];
                        sr[s0] = sr[s1]; si[s0] = si[s1];
                        sr[s1] = tr;     si[s1] = ti;
                    }
                }
            }
        }
        #pragma unroll
        for (int s = 0; s < 16; ++s) { Ur[s][tid] = sr[s]; Ui[s][tid] = si[s]; }
    } else {
        for (int idx = tid - 16; idx < 129*17; idx += 240) {
            int py = idx / 17, pc = idx - py*17;
            int gy = min(py, HH - 1);
            int gx = min(x0 + pc, WW - 1);
            float th = img[gy*WW + gx];
            float sn, cs;
            __sincosf(th, &sn, &cs);
            px[py][pc] = make_float2(cs, sn);
        }
    }
    __syncthreads();

    // ---- phase 2: A_q[t][t'] = sum_s sign_q(s) * Re(conj(U[s,t]) U[s,t']) ----
    for (int e = tid; e < 1024; e += 256) {
        int q = e >> 8, t = (e >> 4) & 15, tp = e & 15;
        float acc = 0.f;
        #pragma unroll
        for (int s = 0; s < 16; ++s) {
            float d = Ur[s][t]*Ur[s][tp] + Ui[s][t]*Ui[s][tp];
            acc += ((s >> (3 - q)) & 1) ? -d : d;
        }
        Amat[q][t][tp] = acc;
    }
    __syncthreads();

    // ---- phase 3: coefficient tensor (generic build, values authoritative) ----
    for (int e = tid; e < 324; e += 256) {     // grid-stride: 324 > 256
        int q = e / 81, kk = e % 81;
        int k0 = kk/27, k1 = (kk/9)%3, k2 = (kk/3)%3, k3 = kk%3;
        int mask = 0, sb = 0;
        if (k0 == 2) mask |= 8; else if (k0 == 1) sb |= 8;
        if (k1 == 2) mask |= 4; else if (k1 == 1) sb |= 4;
        if (k2 == 2) mask |= 2; else if (k2 == 1) sb |= 2;
        if (k3 == 2) mask |= 1; else if (k3 == 1) sb |= 1;
        float acc = 0.f;
        #pragma unroll
        for (int t = 0; t < 16; ++t) {
            float a = Amat[q][t][t ^ mask];
            acc += (__popc(t & sb) & 1) ? -a : a;
        }
        C[q][k0*3 + k1][k2*3 + k3] = acc * 0.0625f;
    }
    __syncthreads();

    // ---- read the 12 structurally-nonzero coefficients (LDS broadcast) ----
    const float c041 = C[0][4][1], c047 = C[0][4][7];
    const float c134 = C[1][3][4], c154 = C[1][5][4];
    const float c211 = C[2][1][1], c217 = C[2][1][7];
    const float c271 = C[2][7][1], c277 = C[2][7][7];
    const float c333 = C[3][3][3], c335 = C[3][3][5];
    const float c353 = C[3][5][3], c355 = C[3][5][5];

    // ---- patch evaluation: 4 y-iters x (2 vertical patches / thread) ----
    // Row components: t1=cosR, t3=cosL, t4=cL*cR, t5=cL*sR, t7=sL*cR.
    // outA uses (row0=T01, row1=T23); outB uses (row1, row2).
    const int tx = tid & 15, ty = tid >> 4;
    const int c  = x0 + tx;

    #pragma unroll 1
    for (int yi = 0; yi < 4; ++yi) {
        const int rA = yi*32 + 2*ty;           // patch A row; B = rA+1 (max 126)

        float2 pL0 = px[rA  ][tx], pR0 = px[rA  ][tx+1];
        float2 pL1 = px[rA+1][tx], pR1 = px[rA+1][tx+1];
        float2 pL2 = px[rA+2][tx], pR2 = px[rA+2][tx+1];

        float r0t1=pR0.x, r0t3=pL0.x, r0t4=pL0.x*pR0.x, r0t5=pL0.x*pR0.y, r0t7=pL0.y*pR0.x;
        float r1t1=pR1.x, r1t3=pL1.x, r1t4=pL1.x*pR1.x, r1t5=pL1.x*pR1.y, r1t7=pL1.y*pR1.x;
        float r2t1=pR2.x, r2t3=pL2.x, r2t4=pL2.x*pR2.x, r2t5=pL2.x*pR2.y, r2t7=pL2.y*pR2.x;

        // patch A
        float oA0 = r0t4 * fmaf(c041, r1t1, c047*r1t7);
        float oA1 = r1t4 * fmaf(c134, r0t3, c154*r0t5);
        float oA2 = fmaf(r0t7, fmaf(c271, r1t1, c277*r1t7),
                         r0t1 * fmaf(c211, r1t1, c217*r1t7));
        float oA3 = fmaf(r0t5, fmaf(c353, r1t3, c355*r1t5),
                         r0t3 * fmaf(c333, r1t3, c335*r1t5));
        // patch B
        float oB0 = r1t4 * fmaf(c041, r2t1, c047*r2t7);
        float oB1 = r2t4 * fmaf(c134, r1t3, c154*r1t5);
        float oB2 = fmaf(r1t7, fmaf(c271, r2t1, c277*r2t7),
                         r1t1 * fmaf(c211, r2t1, c217*r2t7));
        float oB3 = fmaf(r1t5, fmaf(c353, r2t3, c355*r2t5),
                         r1t3 * fmaf(c333, r2t3, c335*r2t5));

        if (c < WO) {
            // rA <= 126 < HO always; guard only row rA+1
            *reinterpret_cast<float4*>(out + ((size_t)((size_t)b*HO + rA)*WO + c)*4) =
                make_float4(oA0, oA1, oA2, oA3);
            if (rA + 1 < HO)
                *reinterpret_cast<float4*>(out + ((size_t)((size_t)b*HO + rA+1)*WO + c)*4) =
                    make_float4(oB0, oB1, oB2, oB3);
        }
    }
}

extern "C" void kernel_launch(void* const* d_in, const int* in_sizes, int n_in,
                              void* d_out, int out_size, void* d_ws, size_t ws_size,
                              hipStream_t stream) {
    const float* images  = (const float*)d_in[0];   // [64,128,128,1]
    const float* weights = (const float*)d_in[1];   // [2,4]
    float* outp = (float*)d_out;                    // [64,127,127,4]

    // 512 blocks = 2 per CU: every CU pays the per-block C-build once,
    // both resident blocks' setups overlap.
    dim3 grid(8, 1, 64);   // 16 cols x 127 patch-rows per block (4 y-iters)
    qconv_fused<<<grid, dim3(256,1,1), 0, stream>>>(images, weights, outp);
}